// Round 3
// baseline (291.751 us; speedup 1.0000x reference)
//
#include <hip/hip_runtime.h>
#include <hip/hip_bf16.h>

// SignMaskLinear: out[t,o] = sum_k x[t,k] * sign(W[o,k]) + b[o]
// R3: single fused kernel. Each block owns a unique 128-row m-stripe:
//   phase 1: quantize its x rows (per-row absmax, i8) directly into LDS
//   phase 2: loop n-tiles; B = sign(W) i8 (tiny prepass) staged per k-iter
//            via global_load_lds; mfma_i32_16x16x64_i8; dequant+bias epilogue.
// Eliminates the xq HBM round-trip (64 MiB) and one big dispatch.
// LDS: A 128x1040 (pad -> 2-way bank aliasing, free) + B 2x8KB + scales
//    = 150,016 B (gfx950 addressable LDS = 160 KiB). 1 block/CU, 8 waves.

typedef int   i32x4 __attribute__((ext_vector_type(4)));

#define APITCH 1040

__device__ __forceinline__ void async16(const void* gptr, void* lptr) {
    __builtin_amdgcn_global_load_lds(
        (const __attribute__((address_space(1))) unsigned int*)gptr,
        (__attribute__((address_space(3))) unsigned int*)lptr,
        16, 0, 0);
}

__device__ __forceinline__ int clamp127(int v) {
    v = v > 127 ? 127 : v;
    v = v < -127 ? -127 : v;
    return v;
}

__device__ __forceinline__ int pack4(int a, int b, int c, int d) {
    return (a & 255) | ((b & 255) << 8) | ((c & 255) << 16) | ((d & 255) << 24);
}

__device__ __forceinline__ int sgnb(float v) {
    return (v > 0.0f) ? 1 : ((v < 0.0f) ? -1 : 0);
}

__device__ __forceinline__ int quant4(const float4 v, float inv) {
    return pack4(clamp127(__float2int_rn(v.x * inv)),
                 clamp127(__float2int_rn(v.y * inv)),
                 clamp127(__float2int_rn(v.z * inv)),
                 clamp127(__float2int_rn(v.w * inv)));
}

// ---- tiny W-sign prepass ------------------------------------------------

__global__ __launch_bounds__(256)
void w_sign(const float* __restrict__ w, signed char* __restrict__ wq, long nw) {
    long i = ((long)blockIdx.x * 256 + threadIdx.x) * 8;
    if (i + 8 > nw) return;
    const float4* p = (const float4*)(w + i);
    float4 a = p[0];
    float4 b = p[1];
    int2 v;
    v.x = pack4(sgnb(a.x), sgnb(a.y), sgnb(a.z), sgnb(a.w));
    v.y = pack4(sgnb(b.x), sgnb(b.y), sgnb(b.z), sgnb(b.w));
    *(int2*)(wq + i) = v;
}

// ---- fused quant + GEMM (requires K == 1024) ----------------------------

__global__ __launch_bounds__(512, 2)
void fused_gemm(const float* __restrict__ x, const signed char* __restrict__ Bq,
                const float* __restrict__ bias, float* __restrict__ C,
                int M, int N) {
    constexpr int K = 1024;
    __shared__ __align__(16) signed char sA[128 * APITCH];  // 133,120 B
    __shared__ __align__(16) signed char sB[16384];         // 2 n-tiles x 8 KB
    __shared__ float sScale[128];

    const int tid  = threadIdx.x;
    const int wave = tid >> 6;
    const int lane = tid & 63;
    const int bm   = blockIdx.x * 128;

    // ---- phase 1: quantize this block's 128 x-rows into sA (i8) ----
    {
        const float* xb = x + (long)bm * K;
#pragma unroll 2
        for (int rr = 0; rr < 16; ++rr) {
            const int row = wave * 16 + rr;
            const float4* p = (const float4*)(xb + (long)row * K + lane * 16);
            float4 v0 = p[0], v1 = p[1], v2 = p[2], v3 = p[3];
            float m = fmaxf(fmaxf(fabsf(v0.x), fabsf(v0.y)), fmaxf(fabsf(v0.z), fabsf(v0.w)));
            m = fmaxf(m, fmaxf(fmaxf(fabsf(v1.x), fabsf(v1.y)), fmaxf(fabsf(v1.z), fabsf(v1.w))));
            m = fmaxf(m, fmaxf(fmaxf(fabsf(v2.x), fabsf(v2.y)), fmaxf(fabsf(v2.z), fabsf(v2.w))));
            m = fmaxf(m, fmaxf(fmaxf(fabsf(v3.x), fabsf(v3.y)), fmaxf(fabsf(v3.z), fabsf(v3.w))));
#pragma unroll
            for (int off = 32; off > 0; off >>= 1)
                m = fmaxf(m, __shfl_xor(m, off, 64));
            const float inv = (m > 0.0f) ? (127.0f / m) : 0.0f;
            i32x4 q;
            q[0] = quant4(v0, inv);
            q[1] = quant4(v1, inv);
            q[2] = quant4(v2, inv);
            q[3] = quant4(v3, inv);
            *(i32x4*)&sA[(long)row * APITCH + lane * 16] = q;
            if (lane == 0) sScale[row] = m * (1.0f / 127.0f);
        }
    }
    __syncthreads();

    // ---- phase 2: n-tile loop, 2 tiles per pass (wave-groups of 4) ----
    const int grp  = wave >> 2;         // 0/1: which of the 2 concurrent n-tiles
    const int w4   = wave & 3;
    const int wrow = (w4 >> 1) * 64;
    const int wcol = (w4 & 1) * 64;
    const int quad = lane >> 4;
    const int l16  = lane & 15;

    // B staging ids: thread t stages tile tt, row srow (+64), 16B chunk sc.
    // Global k-chunk XOR-swizzled by (srow&3): LDS dest must stay linear
    // (global_load_lds = wave-uniform base + lane*16), so swizzle the
    // GLOBAL address; readers un-swizzle. Cuts 8-way LDS conflicts to 4-way.
    const int tt   = tid >> 8;
    const int idx  = tid & 255;
    const int srow = idx >> 2;
    const int sc   = idx & 3;
    const int c0   = (sc ^ (srow & 3)) * 16;

    for (int nt = 0; nt < N / 128; nt += 2) {
        i32x4 acc[4][4] = {};
        const signed char* bq = Bq + (long)((nt + tt) * 128 + srow) * K + c0;
        for (int k0 = 0; k0 < K; k0 += 64) {
            async16(bq + k0, (char*)sB + tt * 8192 + idx * 16);
            async16(bq + (long)64 * K + k0, (char*)sB + tt * 8192 + 4096 + idx * 16);
            __syncthreads();

            i32x4 af[4], bf[4];
#pragma unroll
            for (int i = 0; i < 4; ++i)
                af[i] = *(const i32x4*)&sA[(long)(wrow + i * 16 + l16) * APITCH + k0 + quad * 16];
#pragma unroll
            for (int j = 0; j < 4; ++j) {
                const int r2 = wcol + j * 16 + l16;
                bf[j] = *(const i32x4*)&sB[grp * 8192 + r2 * 64 + ((quad ^ (r2 & 3)) * 16)];
            }
#pragma unroll
            for (int i = 0; i < 4; ++i)
#pragma unroll
                for (int j = 0; j < 4; ++j)
                    acc[i][j] = __builtin_amdgcn_mfma_i32_16x16x64_i8(af[i], bf[j], acc[i][j], 0, 0, 0);

            __syncthreads();
        }

        // epilogue: C/D layout col=l16, row=quad*4+reg (HW-verified R1/R2)
        const int bn0 = (nt + grp) * 128;
#pragma unroll
        for (int j = 0; j < 4; ++j) {
            const int col = bn0 + wcol + j * 16 + l16;
            const float bv = bias[col];
#pragma unroll
            for (int i = 0; i < 4; ++i) {
                const int rl = wrow + i * 16 + quad * 4;
#pragma unroll
                for (int r = 0; r < 4; ++r)
                    C[(long)(bm + rl + r) * N + col] = (float)acc[i][j][r] * sScale[rl + r] + bv;
            }
        }
    }
}

// ---- R2 split path (shape fallback, HW-verified) ------------------------

#define BM 128
#define BN 128
#define BK 64

__global__ __launch_bounds__(256)
void quant_pre(const float* __restrict__ x, const float* __restrict__ w,
               signed char* __restrict__ xq, signed char* __restrict__ wq,
               float* __restrict__ scales, int M, int K, long nw, int xblocks) {
    const int tid = threadIdx.x;
    if ((int)blockIdx.x >= xblocks) {
        long i = ((long)(blockIdx.x - xblocks) * 256 + tid) * 8;
        if (i + 8 > nw) return;
        const float4* p = (const float4*)(w + i);
        float4 a = p[0];
        float4 b = p[1];
        int2 v;
        v.x = pack4(sgnb(a.x), sgnb(a.y), sgnb(a.z), sgnb(a.w));
        v.y = pack4(sgnb(b.x), sgnb(b.y), sgnb(b.z), sgnb(b.w));
        *(int2*)(wq + i) = v;
        return;
    }
    const int wv   = tid >> 6;
    const int lane = tid & 63;
    const int row  = blockIdx.x * 4 + wv;
    if (row >= M) return;
    const float* xr = x + (long)row * K;
    const int chunks = K >> 8;
    float4 v[8];
    float m = 0.0f;
#pragma unroll
    for (int q = 0; q < 8; ++q) {
        if (q >= chunks) break;
        v[q] = *(const float4*)(xr + q * 256 + lane * 4);
        m = fmaxf(m, fmaxf(fmaxf(fabsf(v[q].x), fabsf(v[q].y)),
                           fmaxf(fabsf(v[q].z), fabsf(v[q].w))));
    }
#pragma unroll
    for (int off = 32; off > 0; off >>= 1)
        m = fmaxf(m, __shfl_xor(m, off, 64));
    const float inv = (m > 0.0f) ? (127.0f / m) : 0.0f;
    int* qr = (int*)(xq + (long)row * K);
#pragma unroll
    for (int q = 0; q < 8; ++q) {
        if (q >= chunks) break;
        qr[q * 64 + lane] = quant4(v[q], inv);
    }
    if (lane == 0) scales[row] = m * (1.0f / 127.0f);
}

__global__ __launch_bounds__(256)
void gemm_i8(const signed char* __restrict__ A, const signed char* __restrict__ B,
             const float* __restrict__ scales, const float* __restrict__ bias,
             float* __restrict__ C, int M, int N, int K, int swz) {
    __shared__ __align__(16) signed char sA2[BM * BK];
    __shared__ __align__(16) signed char sB2[BN * BK];
    const int tid  = threadIdx.x;
    const int lane = tid & 63;
    const int wave = tid >> 6;
    const int gn = N / BN;
    int mt, nt;
    if (swz) {
        const int b    = blockIdx.x;
        const int xcd  = b & 7;
        const int rest = b >> 3;
        nt = rest % gn;
        mt = (rest / gn) * 8 + xcd;
    } else {
        nt = blockIdx.x % gn;
        mt = blockIdx.x / gn;
    }
    const int bm = mt * BM;
    const int bn = nt * BN;
    const int wrow = (wave >> 1) * 64;
    const int wcol = (wave & 1) * 64;
    const int quad = lane >> 4;
    const int l16  = lane & 15;
    i32x4 acc[4][4] = {};
    const int row0  = tid >> 2;
    const int col16 = (tid & 3) * 16;
    const signed char* pa0 = A + (long)(bm + row0) * K + col16;
    const signed char* pa1 = pa0 + (long)64 * K;
    const signed char* pb0 = B + (long)(bn + row0) * K + col16;
    const signed char* pb1 = pb0 + (long)64 * K;
    for (int k0 = 0; k0 < K; k0 += BK) {
        async16(pa0 + k0, (char*)sA2 + tid * 16);
        async16(pa1 + k0, (char*)sA2 + (256 + tid) * 16);
        async16(pb0 + k0, (char*)sB2 + tid * 16);
        async16(pb1 + k0, (char*)sB2 + (256 + tid) * 16);
        __syncthreads();
        i32x4 af[4], bfr[4];
#pragma unroll
        for (int i = 0; i < 4; ++i) {
            af[i]  = *(const i32x4*)&sA2[(wrow + i * 16 + l16) * BK + quad * 16];
            bfr[i] = *(const i32x4*)&sB2[(wcol + i * 16 + l16) * BK + quad * 16];
        }
#pragma unroll
        for (int i = 0; i < 4; ++i)
#pragma unroll
            for (int j = 0; j < 4; ++j)
                acc[i][j] = __builtin_amdgcn_mfma_i32_16x16x64_i8(af[i], bfr[j], acc[i][j], 0, 0, 0);
        __syncthreads();
    }
#pragma unroll
    for (int j = 0; j < 4; ++j) {
        const int col = bn + wcol + j * 16 + l16;
        const float bv = bias[col];
#pragma unroll
        for (int i = 0; i < 4; ++i) {
            const int rbase = bm + wrow + i * 16 + quad * 4;
#pragma unroll
            for (int r = 0; r < 4; ++r) {
                const int row = rbase + r;
                C[(long)row * N + col] = (float)acc[i][j][r] * scales[row] + bv;
            }
        }
    }
}

// ---- naive fallback ------------------------------------------------------

__device__ __forceinline__ float signf(float v) {
    return (v > 0.0f) ? 1.0f : ((v < 0.0f) ? -1.0f : 0.0f);
}

__global__ void fallback_kernel(const float* __restrict__ x, const float* __restrict__ w,
                                const float* __restrict__ b, float* __restrict__ out,
                                int M, int N, int K) {
    long o = (long)blockIdx.x * blockDim.x + threadIdx.x;
    if (o >= (long)M * N) return;
    int t = (int)(o / N);
    int n = (int)(o % N);
    const float* xr = x + (long)t * K;
    const float* wr = w + (long)n * K;
    float s = 0.0f;
    for (int k = 0; k < K; ++k) s += xr[k] * signf(wr[k]);
    out[o] = s + b[n];
}

// ---- launch -------------------------------------------------------------

extern "C" void kernel_launch(void* const* d_in, const int* in_sizes, int n_in,
                              void* d_out, int out_size, void* d_ws, size_t ws_size,
                              hipStream_t stream) {
    const float* x = (const float*)d_in[0];
    const float* w = (const float*)d_in[1];
    const float* b = (const float*)d_in[2];
    float* out = (float*)d_out;

    const int N = in_sizes[2];
    const int K = in_sizes[1] / N;
    const int M = in_sizes[0] / K;

    const long nx = (long)M * K;
    const long nw = (long)N * K;

    const bool fused_ok = (K == 1024) && (M % 128 == 0) && (N % 256 == 0) &&
                          (nw % 2048 == 0) && (ws_size >= (size_t)nw + 64);
    if (fused_ok) {
        signed char* wq = (signed char*)d_ws;
        w_sign<<<(int)(nw / 2048), 256, 0, stream>>>(w, wq, nw);
        fused_gemm<<<M / 128, 512, 0, stream>>>(x, wq, b, out, M, N);
        return;
    }

    const size_t need = (size_t)nx + (size_t)nw + (size_t)M * 4 + 64;
    const bool split_ok = (M % BM == 0) && (N % BN == 0) && (K % BK == 0) &&
                          (K % 256 == 0) && (K <= 2048) && (nw % 2048 == 0) &&
                          (ws_size >= need);
    if (split_ok) {
        signed char* xq = (signed char*)d_ws;
        signed char* wq = xq + nx;
        float* scales   = (float*)(wq + nw);
        const int xblocks = M / 4;
        const int wblocks = (int)(nw / 2048);
        quant_pre<<<xblocks + wblocks, 256, 0, stream>>>(x, w, xq, wq, scales, M, K, nw, xblocks);
        const int gm = M / BM, gn = N / BN;
        const int swz = (gm % 8 == 0) ? 1 : 0;
        gemm_i8<<<gm * gn, 256, 0, stream>>>(xq, wq, scales, b, out, M, N, K, swz);
        return;
    }

    long total = (long)M * N;
    int blocks = (int)((total + 255) / 256);
    fallback_kernel<<<blocks, 256, 0, stream>>>(x, w, b, out, M, N, K);
}